// Round 17
// baseline (87.933 us; speedup 1.0000x reference)
//
#include <hip/hip_runtime.h>

#define TPB   256    // threads per block (4 waves)
#define QPT   8      // query points per thread (nn phase)
#define SPLIT 32     // database slices per direction
#define CPB   16     // query chunks per (dir,b) in reduce -> nred = 2*B*CPB
#define MAXRED 256   // max reducer partials supported
#define MAGIC 0x5AD00D5Au

typedef float f32x2 __attribute__((ext_vector_type(2)));

// ============================================================================
// ROUND 17 = R16 with the fence spelled portably: __atomic_thread_fence
// (clang builtin; __hip_atomic_fence doesn't exist in this ROCm).
// Single node; RELAXED spin polls (no per-poll cache invalidation -- R15's
// 85us pathology) + ONE acquire fence per block after the spin. Protocol,
// replay reset, and all compute verbatim R15/R16 (R15 PASSED functionally).
// ============================================================================

__device__ __forceinline__ void block_reduce2(float& s, float& cc, float* red) {
    int tid = threadIdx.x;
    red[tid] = s;
    red[TPB + tid] = cc;
    __syncthreads();
    for (int o = TPB / 2; o > 0; o >>= 1) {
        if (tid < o) {
            red[tid]       += red[tid + o];
            red[TPB + tid] += red[TPB + tid + o];
        }
        __syncthreads();
    }
    s  = red[0];
    cc = red[TPB];
    __syncthreads();
}

__global__ void __launch_bounds__(TPB, 2) fused_kernel(
    const float* __restrict__ pred,
    const float* __restrict__ target,
    const int*   __restrict__ label,
    float* __restrict__ minsplit,          // [2][B][SPLIT][stride]
    float* __restrict__ pS, float* __restrict__ pC,   // [nred]
    unsigned int* __restrict__ nnflag,     // [gridDim.x]
    unsigned int* __restrict__ redflag,    // [nred]
    float* __restrict__ out,
    int B, int N, int M, int natmax, int stride)
{
    __shared__ float xs[TPB], ys[TPB], zs[TPB], ws[TPB];
    __shared__ float red[2 * TPB];

    const int bid = blockIdx.x;
    const int per_dir = B * natmax * SPLIT;

    // -------------------- phase 1: nn (all blocks) --------------------
    {
        const int dir = bid / per_dir;
        const int r1  = bid - dir * per_dir;
        const int b   = r1 / (natmax * SPLIT);
        const int r2  = r1 - b * (natmax * SPLIT);
        const int at  = r2 / SPLIT;
        const int sp  = r2 - at * SPLIT;

        const float* __restrict__ A  = dir ? target : pred;
        const float* __restrict__ Bp = dir ? pred   : target;
        const int NA = dir ? M : N;
        const int NB = dir ? N : M;
        const int* __restrict__ labB = dir ? label : nullptr;

        const int natiles = (NA + TPB * QPT - 1) / (TPB * QPT);
        if (at < natiles) {
            const size_t abase = (size_t)b * NA;

            float px[QPT], py[QPT], pz[QPT], pn[QPT];
            f32x2 best2[QPT];
#pragma unroll
            for (int q = 0; q < QPT; ++q) {
                int a = at * (TPB * QPT) + q * TPB + threadIdx.x;
                int idx = (a < NA) ? a : 0;
                const float* spq = A + (abase + idx) * 3;
                px[q] = spq[0];
                py[q] = spq[1];
                pz[q] = spq[2];
                pn[q] = fmaf(px[q], px[q], fmaf(py[q], py[q], pz[q] * pz[q]));
                best2[q] = (f32x2){3.0e38f, 3.0e38f};
            }

            const int slen = (NB + SPLIT - 1) / SPLIT;
            const int sbeg = sp * slen;
            const int send = min(sbeg + slen, NB);
            const size_t bbase = (size_t)b * NB;

            for (int c = sbeg; c < send; c += TPB) {
                const int cnt = min(send - c, TPB);
                if (threadIdx.x < cnt) {
                    int m = c + threadIdx.x;
                    const float* spm = Bp + (bbase + m) * 3;
                    float x = spm[0], y = spm[1], z = spm[2];
                    float tn = fmaf(x, x, fmaf(y, y, z * z));
                    if (labB != nullptr && labB[bbase + m] != 1) {  // invalid
                        x = 0.0f; y = 0.0f; z = 0.0f; tn = 1.0e10f;
                    }
                    xs[threadIdx.x] = -2.0f * x;
                    ys[threadIdx.x] = -2.0f * y;
                    zs[threadIdx.x] = -2.0f * z;
                    ws[threadIdx.x] = tn;
                }
                __syncthreads();

                const int npair = cnt >> 1;
#pragma unroll 4
                for (int jp = 0; jp < npair; ++jp) {
                    f32x2 tx = *reinterpret_cast<const f32x2*>(&xs[2 * jp]);
                    f32x2 ty = *reinterpret_cast<const f32x2*>(&ys[2 * jp]);
                    f32x2 tz = *reinterpret_cast<const f32x2*>(&zs[2 * jp]);
                    f32x2 tw = *reinterpret_cast<const f32x2*>(&ws[2 * jp]);
#pragma unroll
                    for (int q = 0; q < QPT; ++q) {
                        f32x2 vx = {px[q], px[q]};
                        f32x2 vy = {py[q], py[q]};
                        f32x2 vz = {pz[q], pz[q]};
                        f32x2 v = __builtin_elementwise_fma(vx, tx,
                                  __builtin_elementwise_fma(vy, ty,
                                  __builtin_elementwise_fma(vz, tz, tw)));
                        best2[q] = __builtin_elementwise_min(best2[q], v);
                    }
                }
                if (cnt & 1) {
                    float tx = xs[cnt - 1], ty = ys[cnt - 1];
                    float tz = zs[cnt - 1], tw = ws[cnt - 1];
#pragma unroll
                    for (int q = 0; q < QPT; ++q) {
                        float v = fmaf(px[q], tx, fmaf(py[q], ty, fmaf(pz[q], tz, tw)));
                        best2[q].x = fminf(best2[q].x, v);
                    }
                }
                __syncthreads();
            }

            float* o = minsplit + (((size_t)dir * B + b) * SPLIT + sp) * stride;
#pragma unroll
            for (int q = 0; q < QPT; ++q) {
                int a = at * (TPB * QPT) + q * TPB + threadIdx.x;
                if (a < NA) {
                    float best = fminf(best2[q].x, best2[q].y);
                    o[a] = fmaxf(best + pn[q], 0.0f);
                }
            }
        }
    }

    // release: this block's nn output is published
    __threadfence();
    if (threadIdx.x == 0) {
        atomicExch(&nnflag[bid], MAGIC);
    }

    // -------------------- phase 2: reduce (1 in rstride blocks) ---------
    const int rstride = (natmax * SPLIT) / CPB;       // 4 for 4x4096 shape
    const int nred = 2 * B * CPB;

    if ((bid % rstride) == 0) {
        const int rid = bid / rstride;                // [0, nred)
        const int dir = rid / (B * CPB);
        const int rem = rid - dir * (B * CPB);
        const int b   = rem / CPB;
        const int ch  = rem - b * CPB;
        const int NA  = dir ? M : N;

        // acquire: wait for the 64 nn blocks of (dir,b). RELAXED polls (no
        // per-iteration cache invalidation), one acquire fence afterwards.
        const int fbase  = dir * per_dir + b * (natmax * SPLIT);
        const int nflags = natmax * SPLIT;
        for (int i = threadIdx.x; i < nflags; i += TPB) {
            while (__hip_atomic_load(&nnflag[fbase + i], __ATOMIC_RELAXED,
                                     __HIP_MEMORY_SCOPE_AGENT) != MAGIC) {
                __builtin_amdgcn_s_sleep(2);
            }
        }
        __syncthreads();
        __atomic_thread_fence(__ATOMIC_ACQUIRE);   // one fence-based acquire

        const int qc  = (NA + CPB - 1) / CPB;         // queries per chunk
        const int qpt = (qc + TPB - 1) / TPB;
        const float* base = minsplit + ((size_t)(dir * B + b) * SPLIT) * stride;

        float s = 0.0f, cc = 0.0f;
        for (int k = 0; k < qpt; ++k) {
            int q = ch * qc + k * TPB + threadIdx.x;  // coalesced
            if (q < min((ch + 1) * qc, NA)) {
                float m = base[q];
#pragma unroll 8
                for (int sp = 1; sp < SPLIT; ++sp) {
                    m = fminf(m, base[(size_t)sp * stride + q]);
                }
                if (dir == 0) {
                    if (label[(size_t)b * N + q] == 1) { s += sqrtf(m); cc += 1.0f; }
                } else {
                    s += sqrtf(m);
                }
            }
        }

        block_reduce2(s, cc, red);

        if (threadIdx.x == 0) {
            pS[rid] = s;
            pC[rid] = cc;
            __threadfence();
            atomicExch(&redflag[rid], MAGIC);
        }
    }

    // -------------------- phase 3: combine + flag reset (block 0) -------
    if (bid == 0) {
        for (int i = threadIdx.x; i < nred; i += TPB) {
            while (__hip_atomic_load(&redflag[i], __ATOMIC_RELAXED,
                                     __HIP_MEMORY_SCOPE_AGENT) != MAGIC) {
                __builtin_amdgcn_s_sleep(2);
            }
        }
        __syncthreads();
        __atomic_thread_fence(__ATOMIC_ACQUIRE);

        __shared__ float sS[MAXRED], sC[MAXRED];
        for (int i = threadIdx.x; i < nred; i += TPB) {
            sS[i] = atomicAdd(&pS[i], 0.0f);          // coherent parallel reads
            sC[i] = atomicAdd(&pC[i], 0.0f);
        }
        __syncthreads();

        if (threadIdx.x == 0) {
            float acc = 0.0f;
            for (int bb = 0; bb < B; ++bb) {
                float S1 = 0.0f, C1 = 0.0f, S2 = 0.0f;
                for (int i = 0; i < CPB; ++i) {
                    S1 += sS[bb * CPB + i];
                    C1 += sC[bb * CPB + i];
                    S2 += sS[B * CPB + bb * CPB + i];
                }
                float m1 = S1 / fmaxf(C1, 1.0f);
                float m2 = S2 / (float)M;
                acc += 0.5f * (m1 + m2);
            }
            out[0] = acc / (float)B;   // * LOSS_WEIGHT (== 1.0)
        }
        __syncthreads();

        // reset flags for the next graph replay (flags are dead now; the
        // kernel boundary publishes these plain stores)
        for (int i = threadIdx.x; i < 2 * per_dir; i += TPB) nnflag[i] = 0u;
        for (int i = threadIdx.x; i < nred; i += TPB)        redflag[i] = 0u;
    }
}

// ---------------------------------------------------------------------------
extern "C" void kernel_launch(void* const* d_in, const int* in_sizes, int n_in,
                              void* d_out, int out_size, void* d_ws, size_t ws_size,
                              hipStream_t stream) {
    const float* pred   = (const float*)d_in[0];  // B*N*3 f32
    const float* target = (const float*)d_in[1];  // B*M*3 f32
    const int*   label  = (const int*)  d_in[2];  // B*N   i32

    const int B = in_sizes[3];                 // nums has shape (B,)
    const int N = in_sizes[2] / B;             // label is B*N
    const int M = in_sizes[1] / (3 * B);       // target is B*M*3

    const int stride = (N > M) ? N : M;

    // workspace layout (~4.2 MiB of the provided scratch)
    float* minsplit = (float*)d_ws;                               // 2*B*SPLIT*stride
    const int nred = 2 * B * CPB;                                 // 128 partials
    float* pS = minsplit + (size_t)2 * B * SPLIT * stride;        // nred
    float* pC = pS + nred;                                        // nred
    unsigned int* nnflag  = (unsigned int*)(pC + nred);           // grid blocks
    const int nat1 = (N + TPB * QPT - 1) / (TPB * QPT);
    const int nat2 = (M + TPB * QPT - 1) / (TPB * QPT);
    const int natmax = (nat1 > nat2) ? nat1 : nat2;
    const int nblocks = 2 * B * natmax * SPLIT;                   // 512
    unsigned int* redflag = nnflag + nblocks;                     // nred

    fused_kernel<<<nblocks, TPB, 0, stream>>>(pred, target, label, minsplit,
                                              pS, pC, nnflag, redflag,
                                              (float*)d_out,
                                              B, N, M, natmax, stride);
}

// Round 18
// 87.877 us; speedup vs baseline: 1.0006x; 1.0006x over previous
//
#include <hip/hip_runtime.h>

#define TPB   256    // threads per block (4 waves)
#define QPT   8      // query points per thread (nn phase)
#define SPLIT 32     // database slices per direction
#define CPB   16     // query chunks per (dir,b) in reduce -> nred = 2*B*CPB
#define MAXRED 256   // max reducer partials supported
#define MAGIC 0x5AD00D5Au

typedef float f32x2 __attribute__((ext_vector_type(2)));

// ============================================================================
// ROUND 18 = R17 with the spin polls changed from relaxed LOADS to atomic
// RMWs (atomicAdd(flag, 0)). Diagnosis: per-XCD L2s are not coherent; a
// relaxed load can spin on a STALE local-L2 line until chance eviction
// (R17: 92us), while acquire loads invalidate caches every poll (R15: 85us).
// Atomic RMWs execute at the coherence point: always fresh, no cache
// maintenance. One acquire fence per block after the spin orders the
// subsequent data reads. Everything else verbatim R17 (correct, passing).
// ============================================================================

__device__ __forceinline__ void block_reduce2(float& s, float& cc, float* red) {
    int tid = threadIdx.x;
    red[tid] = s;
    red[TPB + tid] = cc;
    __syncthreads();
    for (int o = TPB / 2; o > 0; o >>= 1) {
        if (tid < o) {
            red[tid]       += red[tid + o];
            red[TPB + tid] += red[TPB + tid + o];
        }
        __syncthreads();
    }
    s  = red[0];
    cc = red[TPB];
    __syncthreads();
}

__global__ void __launch_bounds__(TPB, 2) fused_kernel(
    const float* __restrict__ pred,
    const float* __restrict__ target,
    const int*   __restrict__ label,
    float* __restrict__ minsplit,          // [2][B][SPLIT][stride]
    float* __restrict__ pS, float* __restrict__ pC,   // [nred]
    unsigned int* __restrict__ nnflag,     // [gridDim.x]
    unsigned int* __restrict__ redflag,    // [nred]
    float* __restrict__ out,
    int B, int N, int M, int natmax, int stride)
{
    __shared__ float xs[TPB], ys[TPB], zs[TPB], ws[TPB];
    __shared__ float red[2 * TPB];

    const int bid = blockIdx.x;
    const int per_dir = B * natmax * SPLIT;

    // -------------------- phase 1: nn (all blocks) --------------------
    {
        const int dir = bid / per_dir;
        const int r1  = bid - dir * per_dir;
        const int b   = r1 / (natmax * SPLIT);
        const int r2  = r1 - b * (natmax * SPLIT);
        const int at  = r2 / SPLIT;
        const int sp  = r2 - at * SPLIT;

        const float* __restrict__ A  = dir ? target : pred;
        const float* __restrict__ Bp = dir ? pred   : target;
        const int NA = dir ? M : N;
        const int NB = dir ? N : M;
        const int* __restrict__ labB = dir ? label : nullptr;

        const int natiles = (NA + TPB * QPT - 1) / (TPB * QPT);
        if (at < natiles) {
            const size_t abase = (size_t)b * NA;

            float px[QPT], py[QPT], pz[QPT], pn[QPT];
            f32x2 best2[QPT];
#pragma unroll
            for (int q = 0; q < QPT; ++q) {
                int a = at * (TPB * QPT) + q * TPB + threadIdx.x;
                int idx = (a < NA) ? a : 0;
                const float* spq = A + (abase + idx) * 3;
                px[q] = spq[0];
                py[q] = spq[1];
                pz[q] = spq[2];
                pn[q] = fmaf(px[q], px[q], fmaf(py[q], py[q], pz[q] * pz[q]));
                best2[q] = (f32x2){3.0e38f, 3.0e38f};
            }

            const int slen = (NB + SPLIT - 1) / SPLIT;
            const int sbeg = sp * slen;
            const int send = min(sbeg + slen, NB);
            const size_t bbase = (size_t)b * NB;

            for (int c = sbeg; c < send; c += TPB) {
                const int cnt = min(send - c, TPB);
                if (threadIdx.x < cnt) {
                    int m = c + threadIdx.x;
                    const float* spm = Bp + (bbase + m) * 3;
                    float x = spm[0], y = spm[1], z = spm[2];
                    float tn = fmaf(x, x, fmaf(y, y, z * z));
                    if (labB != nullptr && labB[bbase + m] != 1) {  // invalid
                        x = 0.0f; y = 0.0f; z = 0.0f; tn = 1.0e10f;
                    }
                    xs[threadIdx.x] = -2.0f * x;
                    ys[threadIdx.x] = -2.0f * y;
                    zs[threadIdx.x] = -2.0f * z;
                    ws[threadIdx.x] = tn;
                }
                __syncthreads();

                const int npair = cnt >> 1;
#pragma unroll 4
                for (int jp = 0; jp < npair; ++jp) {
                    f32x2 tx = *reinterpret_cast<const f32x2*>(&xs[2 * jp]);
                    f32x2 ty = *reinterpret_cast<const f32x2*>(&ys[2 * jp]);
                    f32x2 tz = *reinterpret_cast<const f32x2*>(&zs[2 * jp]);
                    f32x2 tw = *reinterpret_cast<const f32x2*>(&ws[2 * jp]);
#pragma unroll
                    for (int q = 0; q < QPT; ++q) {
                        f32x2 vx = {px[q], px[q]};
                        f32x2 vy = {py[q], py[q]};
                        f32x2 vz = {pz[q], pz[q]};
                        f32x2 v = __builtin_elementwise_fma(vx, tx,
                                  __builtin_elementwise_fma(vy, ty,
                                  __builtin_elementwise_fma(vz, tz, tw)));
                        best2[q] = __builtin_elementwise_min(best2[q], v);
                    }
                }
                if (cnt & 1) {
                    float tx = xs[cnt - 1], ty = ys[cnt - 1];
                    float tz = zs[cnt - 1], tw = ws[cnt - 1];
#pragma unroll
                    for (int q = 0; q < QPT; ++q) {
                        float v = fmaf(px[q], tx, fmaf(py[q], ty, fmaf(pz[q], tz, tw)));
                        best2[q].x = fminf(best2[q].x, v);
                    }
                }
                __syncthreads();
            }

            float* o = minsplit + (((size_t)dir * B + b) * SPLIT + sp) * stride;
#pragma unroll
            for (int q = 0; q < QPT; ++q) {
                int a = at * (TPB * QPT) + q * TPB + threadIdx.x;
                if (a < NA) {
                    float best = fminf(best2[q].x, best2[q].y);
                    o[a] = fmaxf(best + pn[q], 0.0f);
                }
            }
        }
    }

    // release: this block's nn output is published
    __threadfence();
    if (threadIdx.x == 0) {
        atomicExch(&nnflag[bid], MAGIC);
    }

    // -------------------- phase 2: reduce (1 in rstride blocks) ---------
    const int rstride = (natmax * SPLIT) / CPB;       // 4 for 4x4096 shape
    const int nred = 2 * B * CPB;

    if ((bid % rstride) == 0) {
        const int rid = bid / rstride;                // [0, nred)
        const int dir = rid / (B * CPB);
        const int rem = rid - dir * (B * CPB);
        const int b   = rem / CPB;
        const int ch  = rem - b * CPB;
        const int NA  = dir ? M : N;

        // acquire: wait for the 64 nn blocks of (dir,b). Poll with atomic
        // RMWs (coherence-point reads: fresh, no cache invalidation), then
        // one acquire fence for the data ordering.
        const int fbase  = dir * per_dir + b * (natmax * SPLIT);
        const int nflags = natmax * SPLIT;
        for (int i = threadIdx.x; i < nflags; i += TPB) {
            while (atomicAdd(&nnflag[fbase + i], 0u) != MAGIC) {
                __builtin_amdgcn_s_sleep(4);
            }
        }
        __syncthreads();
        __atomic_thread_fence(__ATOMIC_ACQUIRE);

        const int qc  = (NA + CPB - 1) / CPB;         // queries per chunk
        const int qpt = (qc + TPB - 1) / TPB;
        const float* base = minsplit + ((size_t)(dir * B + b) * SPLIT) * stride;

        float s = 0.0f, cc = 0.0f;
        for (int k = 0; k < qpt; ++k) {
            int q = ch * qc + k * TPB + threadIdx.x;  // coalesced
            if (q < min((ch + 1) * qc, NA)) {
                float m = base[q];
#pragma unroll 8
                for (int sp = 1; sp < SPLIT; ++sp) {
                    m = fminf(m, base[(size_t)sp * stride + q]);
                }
                if (dir == 0) {
                    if (label[(size_t)b * N + q] == 1) { s += sqrtf(m); cc += 1.0f; }
                } else {
                    s += sqrtf(m);
                }
            }
        }

        block_reduce2(s, cc, red);

        if (threadIdx.x == 0) {
            pS[rid] = s;
            pC[rid] = cc;
            __threadfence();
            atomicExch(&redflag[rid], MAGIC);
        }
    }

    // -------------------- phase 3: combine + flag reset (block 0) -------
    if (bid == 0) {
        for (int i = threadIdx.x; i < nred; i += TPB) {
            while (atomicAdd(&redflag[i], 0u) != MAGIC) {
                __builtin_amdgcn_s_sleep(4);
            }
        }
        __syncthreads();
        __atomic_thread_fence(__ATOMIC_ACQUIRE);

        __shared__ float sS[MAXRED], sC[MAXRED];
        for (int i = threadIdx.x; i < nred; i += TPB) {
            sS[i] = atomicAdd(&pS[i], 0.0f);          // coherent parallel reads
            sC[i] = atomicAdd(&pC[i], 0.0f);
        }
        __syncthreads();

        if (threadIdx.x == 0) {
            float acc = 0.0f;
            for (int bb = 0; bb < B; ++bb) {
                float S1 = 0.0f, C1 = 0.0f, S2 = 0.0f;
                for (int i = 0; i < CPB; ++i) {
                    S1 += sS[bb * CPB + i];
                    C1 += sC[bb * CPB + i];
                    S2 += sS[B * CPB + bb * CPB + i];
                }
                float m1 = S1 / fmaxf(C1, 1.0f);
                float m2 = S2 / (float)M;
                acc += 0.5f * (m1 + m2);
            }
            out[0] = acc / (float)B;   // * LOSS_WEIGHT (== 1.0)
        }
        __syncthreads();

        // reset flags for the next graph replay (flags are dead now; the
        // kernel boundary publishes these plain stores)
        for (int i = threadIdx.x; i < 2 * per_dir; i += TPB) nnflag[i] = 0u;
        for (int i = threadIdx.x; i < nred; i += TPB)        redflag[i] = 0u;
    }
}

// ---------------------------------------------------------------------------
extern "C" void kernel_launch(void* const* d_in, const int* in_sizes, int n_in,
                              void* d_out, int out_size, void* d_ws, size_t ws_size,
                              hipStream_t stream) {
    const float* pred   = (const float*)d_in[0];  // B*N*3 f32
    const float* target = (const float*)d_in[1];  // B*M*3 f32
    const int*   label  = (const int*)  d_in[2];  // B*N   i32

    const int B = in_sizes[3];                 // nums has shape (B,)
    const int N = in_sizes[2] / B;             // label is B*N
    const int M = in_sizes[1] / (3 * B);       // target is B*M*3

    const int stride = (N > M) ? N : M;

    // workspace layout (~4.2 MiB of the provided scratch)
    float* minsplit = (float*)d_ws;                               // 2*B*SPLIT*stride
    const int nred = 2 * B * CPB;                                 // 128 partials
    float* pS = minsplit + (size_t)2 * B * SPLIT * stride;        // nred
    float* pC = pS + nred;                                        // nred
    unsigned int* nnflag  = (unsigned int*)(pC + nred);           // grid blocks
    const int nat1 = (N + TPB * QPT - 1) / (TPB * QPT);
    const int nat2 = (M + TPB * QPT - 1) / (TPB * QPT);
    const int natmax = (nat1 > nat2) ? nat1 : nat2;
    const int nblocks = 2 * B * natmax * SPLIT;                   // 512
    unsigned int* redflag = nnflag + nblocks;                     // nred

    fused_kernel<<<nblocks, TPB, 0, stream>>>(pred, target, label, minsplit,
                                              pS, pC, nnflag, redflag,
                                              (float*)d_out,
                                              B, N, M, natmax, stride);
}

// Round 19
// 30.754 us; speedup vs baseline: 2.8592x; 2.8574x over previous
//
#include <hip/hip_runtime.h>

#define TPB   256    // nn threads per block (4 waves)
#define QPT   8      // query points per thread
#define SPLIT 32     // database slices per direction
#define RTPB  256    // reduce threads per block
#define CPB   8      // query chunks per (dir,b) in reduce  -> 2*B*CPB = 64 blocks

typedef float f32x2 __attribute__((ext_vector_type(2)));

// ============================================================================
// ROUND 19 = R13 verbatim (best measured: 30.77 us). Final structure after the
// full ladder:
//   4 nodes: 37.4 | 3 nodes: 35.6 | 2 nodes: 30.8-31.0 (THIS) |
//   1 node (flag-sync, any flavor): 85-92 | cooperative: 227.
// Budget (measured by R10/R14 duplication probes): nn = 9.8 us, reduce ~3 us,
// rest is per-replay launch overhead; 2 nodes is the empirical optimum.
// nn: 512 blocks (2/CU), packed-f32 inner loop (v_pk_fma/v_pk_min via vector
// IR), DB staged SoA as (-2x,-2y,-2z,|t|^2) with label poisoning folded
// (invalid -> coords 0, tn=1e10 == reference BIG). Candidate = 3-fma chain;
// min over it = min over d shifted by |p|^2 (added once per query, clamped
// >= 0). Bit-deterministic (no atomics in hot path, fixed-order reductions).
// reduce_final: 64 blocks; coalesced min over 32 slices, sqrt, masked sums,
// block reduce -> 1 partial pair; atomicExch + counter; last block reads the
// 64 partials in parallel (device-scope atomic reads) and combines in fixed
// order. Counter is zeroed by nn block (0,0,0) each call -> replay-safe.
// ============================================================================

__global__ void __launch_bounds__(TPB) nn_kernel(
    const float* __restrict__ pred,
    const float* __restrict__ target,
    const int*   __restrict__ label,
    float* __restrict__ minsplit,     // [2][B][SPLIT][stride]
    unsigned int* __restrict__ counter,
    int B, int N, int M, int natmax, int stride)
{
    __shared__ float xs[TPB], ys[TPB], zs[TPB], ws[TPB];

    if (blockIdx.x == 0 && blockIdx.y == 0 && blockIdx.z == 0 && threadIdx.x == 0) {
        *counter = 0u;   // consumed by reduce_final (next dispatch) each call
    }

    const int dir = blockIdx.z;
    const float* __restrict__ A  = dir ? target : pred;
    const float* __restrict__ Bp = dir ? pred   : target;
    const int NA = dir ? M : N;
    const int NB = dir ? N : M;
    const int* __restrict__ labB = dir ? label : nullptr;

    const int natiles = (NA + TPB * QPT - 1) / (TPB * QPT);
    const int b  = blockIdx.x / natmax;
    const int at = blockIdx.x - b * natmax;
    if (at >= natiles) return;

    const size_t abase = (size_t)b * NA;

    float px[QPT], py[QPT], pz[QPT], pn[QPT];
    f32x2 best2[QPT];
#pragma unroll
    for (int q = 0; q < QPT; ++q) {
        int a = at * (TPB * QPT) + q * TPB + threadIdx.x;
        int idx = (a < NA) ? a : 0;
        const float* sp = A + (abase + idx) * 3;
        px[q] = sp[0];
        py[q] = sp[1];
        pz[q] = sp[2];
        pn[q] = fmaf(px[q], px[q], fmaf(py[q], py[q], pz[q] * pz[q]));
        best2[q] = (f32x2){3.0e38f, 3.0e38f};
    }

    const int slen = (NB + SPLIT - 1) / SPLIT;
    const int sbeg = blockIdx.y * slen;
    const int send = min(sbeg + slen, NB);
    const size_t bbase = (size_t)b * NB;

    for (int c = sbeg; c < send; c += TPB) {
        const int cnt = min(send - c, TPB);
        if (threadIdx.x < cnt) {
            int m = c + threadIdx.x;
            const float* sp = Bp + (bbase + m) * 3;
            float x = sp[0], y = sp[1], z = sp[2];
            float tn = fmaf(x, x, fmaf(y, y, z * z));
            if (labB != nullptr && labB[bbase + m] != 1) {   // invalid point
                x = 0.0f; y = 0.0f; z = 0.0f; tn = 1.0e10f;
            }
            xs[threadIdx.x] = -2.0f * x;
            ys[threadIdx.x] = -2.0f * y;
            zs[threadIdx.x] = -2.0f * z;
            ws[threadIdx.x] = tn;
        }
        __syncthreads();

        const int npair = cnt >> 1;
#pragma unroll 4
        for (int jp = 0; jp < npair; ++jp) {
            // wave-uniform SoA pair loads (ds_read_b64 broadcast)
            f32x2 tx = *reinterpret_cast<const f32x2*>(&xs[2 * jp]);
            f32x2 ty = *reinterpret_cast<const f32x2*>(&ys[2 * jp]);
            f32x2 tz = *reinterpret_cast<const f32x2*>(&zs[2 * jp]);
            f32x2 tw = *reinterpret_cast<const f32x2*>(&ws[2 * jp]);
#pragma unroll
            for (int q = 0; q < QPT; ++q) {
                f32x2 vx = {px[q], px[q]};
                f32x2 vy = {py[q], py[q]};
                f32x2 vz = {pz[q], pz[q]};
                f32x2 v = __builtin_elementwise_fma(vx, tx,
                          __builtin_elementwise_fma(vy, ty,
                          __builtin_elementwise_fma(vz, tz, tw)));
                best2[q] = __builtin_elementwise_min(best2[q], v);  // v_pk_min
            }
        }
        if (cnt & 1) {
            float tx = xs[cnt - 1], ty = ys[cnt - 1], tz = zs[cnt - 1], tw = ws[cnt - 1];
#pragma unroll
            for (int q = 0; q < QPT; ++q) {
                float v = fmaf(px[q], tx, fmaf(py[q], ty, fmaf(pz[q], tz, tw)));
                best2[q].x = fminf(best2[q].x, v);
            }
        }
        __syncthreads();              // protect SoA tile before next stage
    }

    float* out = minsplit + (((size_t)dir * B + b) * SPLIT + blockIdx.y) * stride;
#pragma unroll
    for (int q = 0; q < QPT; ++q) {
        int a = at * (TPB * QPT) + q * TPB + threadIdx.x;
        if (a < NA) {
            float best = fminf(best2[q].x, best2[q].y);   // exact fold
            out[a] = fmaxf(best + pn[q], 0.0f);
        }
    }
}

// ---------------------------------------------------------------------------
__device__ __forceinline__ void block_reduce2(float& s, float& cc, float* red) {
    int tid = threadIdx.x;
    red[tid] = s;
    red[RTPB + tid] = cc;
    __syncthreads();
    for (int o = RTPB / 2; o > 0; o >>= 1) {
        if (tid < o) {
            red[tid]        += red[tid + o];
            red[RTPB + tid] += red[RTPB + tid + o];
        }
        __syncthreads();
    }
    s  = red[0];
    cc = red[RTPB];
    __syncthreads();
}

__global__ void __launch_bounds__(RTPB) reduce_final_kernel(
    const float* __restrict__ minsplit,
    const int* __restrict__ label,
    float* __restrict__ pS, float* __restrict__ pC,
    unsigned int* __restrict__ counter,
    float* __restrict__ out,
    int B, int N, int M, int stride, int nblocks)
{
    __shared__ float red[2 * RTPB];
    const int r = blockIdx.x;

    const int dir = r / (B * CPB);
    const int rem = r - dir * (B * CPB);
    const int b   = rem / CPB;
    const int ch  = rem - b * CPB;
    const int NA  = dir ? M : N;
    const int qc  = (NA + CPB - 1) / CPB;          // queries per chunk
    const int qpt = (qc + RTPB - 1) / RTPB;        // queries per thread

    const float* base = minsplit + ((size_t)(dir * B + b) * SPLIT) * stride;

    float s = 0.0f, cc = 0.0f;
    for (int k = 0; k < qpt; ++k) {
        int q = ch * qc + k * RTPB + threadIdx.x;  // consecutive tid -> coalesced
        if (q < min((ch + 1) * qc, NA)) {
            float m = base[q];
#pragma unroll 8
            for (int sp = 1; sp < SPLIT; ++sp) {
                m = fminf(m, base[(size_t)sp * stride + q]);
            }
            if (dir == 0) {
                if (label[(size_t)b * N + q] == 1) { s += sqrtf(m); cc += 1.0f; }
            } else {
                s += sqrtf(m);
            }
        }
    }

    block_reduce2(s, cc, red);

    __shared__ unsigned int is_last;
    if (threadIdx.x == 0) {
        atomicExch(&pS[r], s);                 // device-scope, XCD-coherent
        atomicExch(&pC[r], cc);
        __threadfence();
        unsigned int old = atomicAdd(counter, 1u);
        is_last = (old == (unsigned int)(nblocks - 1)) ? 1u : 0u;
    }
    __syncthreads();

    if (is_last) {
        __shared__ float sS[2 * 64], sC[2 * 64];   // nblocks = 2*B*CPB <= 128
        for (int i = threadIdx.x; i < nblocks; i += RTPB) {
            sS[i] = atomicAdd(&pS[i], 0.0f);       // parallel device-scope reads
            sC[i] = atomicAdd(&pC[i], 0.0f);
        }
        __syncthreads();
        if (threadIdx.x == 0) {
            float acc = 0.0f;
            for (int bb = 0; bb < B; ++bb) {
                float S1 = 0.0f, C1 = 0.0f, S2 = 0.0f;
                for (int i = 0; i < CPB; ++i) {
                    S1 += sS[bb * CPB + i];
                    C1 += sC[bb * CPB + i];
                    S2 += sS[B * CPB + bb * CPB + i];
                }
                float m1 = S1 / fmaxf(C1, 1.0f);
                float m2 = S2 / (float)M;
                acc += 0.5f * (m1 + m2);
            }
            out[0] = acc / (float)B;   // * LOSS_WEIGHT (== 1.0)
        }
    }
}

// ---------------------------------------------------------------------------
extern "C" void kernel_launch(void* const* d_in, const int* in_sizes, int n_in,
                              void* d_out, int out_size, void* d_ws, size_t ws_size,
                              hipStream_t stream) {
    const float* pred   = (const float*)d_in[0];  // B*N*3 f32
    const float* target = (const float*)d_in[1];  // B*M*3 f32
    const int*   label  = (const int*)  d_in[2];  // B*N   i32

    const int B = in_sizes[3];                 // nums has shape (B,)
    const int N = in_sizes[2] / B;             // label is B*N
    const int M = in_sizes[1] / (3 * B);       // target is B*M*3

    const int stride = (N > M) ? N : M;

    // workspace layout (~4.2 MiB of the provided scratch)
    float* minsplit = (float*)d_ws;                               // 2*B*SPLIT*stride
    const int nred = 2 * B * CPB;                                 // 64 partials
    float* pS = minsplit + (size_t)2 * B * SPLIT * stride;        // nred
    float* pC = pS + nred;                                        // nred
    unsigned int* counter = (unsigned int*)(pC + nred);

    const int nat1 = (N + TPB * QPT - 1) / (TPB * QPT);
    const int nat2 = (M + TPB * QPT - 1) / (TPB * QPT);
    const int natmax = (nat1 > nat2) ? nat1 : nat2;
    dim3 g(B * natmax, SPLIT, 2);
    nn_kernel<<<g, TPB, 0, stream>>>(pred, target, label, minsplit, counter,
                                     B, N, M, natmax, stride);

    reduce_final_kernel<<<nred, RTPB, 0, stream>>>(minsplit, label, pS, pC,
                                                   counter, (float*)d_out,
                                                   B, N, M, stride, nred);
}